// Round 6
// baseline (367.353 us; speedup 1.0000x reference)
//
#include <hip/hip_runtime.h>

// Problem constants
#define BB   2
#define SS   4096
#define DD   1024
#define HH   16
#define DHH  64
#define WW   256
#define GG   64
#define NBLK 16    // S/W

typedef unsigned short ushort_t;
typedef short  s16x8 __attribute__((ext_vector_type(8)));
typedef float  f32x4 __attribute__((ext_vector_type(4)));

// fp32 -> bf16 round-to-nearest-even, raw bits
__device__ __forceinline__ ushort_t f2b(float f) {
  unsigned int u = __builtin_bit_cast(unsigned int, f);
  unsigned int r = (u + 0x7fffu + ((u >> 16) & 1u)) >> 16;
  return (ushort_t)r;
}

// ---------------------------------------------------------------------------
// Transpose + fp32->bf16 convert the four 1024x1024 weight matrices into
// (n,k) bf16 layout. grid (16,16,4), 256 threads. Outputs contiguous:
// [WqT | WkT | WvT | WoT] at outBase.
// ---------------------------------------------------------------------------
__global__ __launch_bounds__(256) void transpose_w(
    const float* __restrict__ Wq, const float* __restrict__ Wk,
    const float* __restrict__ Wv, const float* __restrict__ Wo,
    ushort_t* __restrict__ outBase) {
  const float* src = (blockIdx.z == 0) ? Wq : (blockIdx.z == 1) ? Wk
                    : (blockIdx.z == 2) ? Wv : Wo;
  ushort_t* dst = outBase + (size_t)blockIdx.z * (1024 * 1024);
  __shared__ __align__(16) ushort_t t[64][72];   // t[col][row]
  const int tid = threadIdx.x;
  const int bx = blockIdx.x * 64, by = blockIdx.y * 64;
  const int c4 = (tid & 15) * 4;
  const int r16 = tid >> 4;
  for (int rr = r16; rr < 64; rr += 16) {
    float4 f = *(const float4*)&src[(size_t)(by + rr) * 1024 + bx + c4];
    t[c4 + 0][rr] = f2b(f.x);
    t[c4 + 1][rr] = f2b(f.y);
    t[c4 + 2][rr] = f2b(f.z);
    t[c4 + 3][rr] = f2b(f.w);
  }
  __syncthreads();
  const int sr = tid >> 3;
  const int sc = (tid & 7) * 8;
  for (int rr = sr; rr < 64; rr += 32) {
    *(uint4*)&dst[(size_t)(bx + rr) * 1024 + by + sc] = *(const uint4*)&t[rr][sc];
  }
}

// ---------------------------------------------------------------------------
// GEMM: C(M,N) = A(M,K) @ Bt(N,K)^T, fp32 acc.
// MODE 0: A is fp32 (x), converted during staging; epilogue splits QKV heads
//         into bf16 (B,H,S,DH) buffers.
// MODE 1: A is bf16 (attn); epilogue writes FP32 row-major C to Of.
// ---------------------------------------------------------------------------
template <int MODE>
__global__ __launch_bounds__(256) void gemm_bt(
    const void* __restrict__ Avoid, const ushort_t* __restrict__ Bt,
    ushort_t* __restrict__ O0, ushort_t* __restrict__ O1,
    ushort_t* __restrict__ O2, float* __restrict__ Of, int K) {
  __shared__ __align__(16) ushort_t As[128 * 64];
  __shared__ __align__(16) ushort_t Bs[128 * 64];
  const int tid  = threadIdx.x;
  const int lane = tid & 63;
  const int w    = tid >> 6;
  const int quad = lane >> 4;
  const int l16  = lane & 15;
  const int bm = blockIdx.x * 128;
  const int bn = blockIdx.y * 128;
  const int sr = tid >> 3;
  const int sc = (tid & 7) * 8;
  const int wm = (w & 1) * 64;
  const int wn = (w >> 1) * 64;

  f32x4 acc[4][4] = {};

  for (int k0 = 0; k0 < K; k0 += 64) {
    __syncthreads();
#pragma unroll
    for (int cpy = 0; cpy < 4; cpy++) {
      int r = sr + cpy * 32;
      if (MODE == 0) {
        const float* Af = (const float*)Avoid;
        float4 f0 = *(const float4*)&Af[(size_t)(bm + r) * K + k0 + sc];
        float4 f1 = *(const float4*)&Af[(size_t)(bm + r) * K + k0 + sc + 4];
        ushort_t tmp[8];
        tmp[0] = f2b(f0.x); tmp[1] = f2b(f0.y); tmp[2] = f2b(f0.z); tmp[3] = f2b(f0.w);
        tmp[4] = f2b(f1.x); tmp[5] = f2b(f1.y); tmp[6] = f2b(f1.z); tmp[7] = f2b(f1.w);
        *(uint4*)&As[r * 64 + sc] = *(const uint4*)tmp;
      } else {
        const ushort_t* Ab = (const ushort_t*)Avoid;
        *(uint4*)&As[r * 64 + sc] = *(const uint4*)&Ab[(size_t)(bm + r) * K + k0 + sc];
      }
      *(uint4*)&Bs[r * 64 + sc] = *(const uint4*)&Bt[(size_t)(bn + r) * K + k0 + sc];
    }
    __syncthreads();
#pragma unroll
    for (int kk = 0; kk < 64; kk += 32) {
      s16x8 a[4], b[4];
#pragma unroll
      for (int t = 0; t < 4; t++)
        a[t] = *(const s16x8*)&As[(wm + t * 16 + l16) * 64 + kk + quad * 8];
#pragma unroll
      for (int t = 0; t < 4; t++)
        b[t] = *(const s16x8*)&Bs[(wn + t * 16 + l16) * 64 + kk + quad * 8];
#pragma unroll
      for (int i = 0; i < 4; i++)
#pragma unroll
        for (int j = 0; j < 4; j++)
          acc[i][j] = __builtin_amdgcn_mfma_f32_16x16x32_bf16(a[i], b[j], acc[i][j], 0, 0, 0);
    }
  }

  // Epilogue. C/D layout: row = quad*4 + reg, col = lane&15.
#pragma unroll
  for (int i = 0; i < 4; i++) {
#pragma unroll
    for (int j = 0; j < 4; j++) {
#pragma unroll
      for (int r = 0; r < 4; r++) {
        int m = bm + wm + i * 16 + quad * 4 + r;
        int n = bn + wn + j * 16 + l16;
        if (MODE == 0) {
          ushort_t val = f2b(acc[i][j][r]);
          ushort_t* dst = (n < 1024) ? O0 : (n < 2048) ? O1 : O2;
          int n1 = n & 1023;
          int h = n1 >> 6, dh = n1 & 63;
          int b = m >> 12, s = m & 4095;
          dst[(((size_t)b * HH + h) * SS + s) * DHH + dh] = val;
        } else {
          Of[(size_t)m * DD + n] = acc[i][j][r];   // FP32 output
        }
      }
    }
  }
}

// ---------------------------------------------------------------------------
// Blocked local+global attention (MFMA). grid (NBLK, H, B), 256 threads =
// 4 waves; wave w owns 64 queries. 13 key-chunks of 64 (12 local + 1 global).
// Two-pass softmax; P round-trips through per-wave LDS tile (C/D -> A layout).
// Verified equivalent to the scalar VALU reference implementation (rounds
// 3 vs 4 produced bit-identical downstream results).
// Output (B, S, H*DH) bf16.
// ---------------------------------------------------------------------------
__global__ __launch_bounds__(256, 2) void attn_kernel(
    const ushort_t* __restrict__ q, const ushort_t* __restrict__ k,
    const ushort_t* __restrict__ v, ushort_t* __restrict__ out) {
  const int blk = blockIdx.x;
  const int h   = blockIdx.y;
  const int b   = blockIdx.z;
  const int tid  = threadIdx.x;
  const int lane = tid & 63;
  const int w    = tid >> 6;
  const int quad = lane >> 4;
  const int l16  = lane & 15;

  const size_t bh = ((size_t)b * HH + h) * SS * DHH;
  const ushort_t* qb = q + bh;
  const ushort_t* kb = k + bh;
  const ushort_t* vb = v + bh;

  __shared__ __align__(16) ushort_t Ks[64 * 64];
  __shared__ __align__(16) ushort_t Vts[64 * 64];     // V transposed: [dh][l]
  __shared__ __align__(16) ushort_t Ps[4][64 * 64];   // per-wave P tile [m][l]

  const int q0 = blk * WW + w * 64;
  const int sr = tid >> 3;
  const int sc = (tid & 7) * 8;
  const float scale = 0.125f;

  s16x8 aq[4][2];
#pragma unroll
  for (int mt = 0; mt < 4; mt++)
#pragma unroll
    for (int x = 0; x < 2; x++)
      aq[mt][x] = *(const s16x8*)&qb[(size_t)(q0 + mt * 16 + l16) * DHH + x * 32 + quad * 8];

  // ---- Pass 1: row maxima ----
  float rmax[4][4];
#pragma unroll
  for (int mt = 0; mt < 4; mt++)
#pragma unroll
    for (int r = 0; r < 4; r++) rmax[mt][r] = -3.0e38f;

  for (int c = 0; c < 13; c++) {
    const int j0 = (c < 12) ? (blk * WW - WW + c * 64) : 0;
    if (c < 12 && (j0 + 63 < GG || j0 >= SS)) continue;
    __syncthreads();
#pragma unroll
    for (int cpy = 0; cpy < 2; cpy++) {
      int r = sr + cpy * 32;
      int j = j0 + r;
      uint4 val = make_uint4(0, 0, 0, 0);
      if (j >= 0 && j < SS) val = *(const uint4*)&kb[(size_t)j * DHH + sc];
      *(uint4*)&Ks[r * 64 + sc] = val;
    }
    __syncthreads();
#pragma unroll
    for (int nt = 0; nt < 4; nt++) {
      s16x8 bk0 = *(const s16x8*)&Ks[(nt * 16 + l16) * 64 + 0 + quad * 8];
      s16x8 bk1 = *(const s16x8*)&Ks[(nt * 16 + l16) * 64 + 32 + quad * 8];
      int j = j0 + nt * 16 + l16;
#pragma unroll
      for (int mt = 0; mt < 4; mt++) {
        f32x4 s4 = {0.f, 0.f, 0.f, 0.f};
        s4 = __builtin_amdgcn_mfma_f32_16x16x32_bf16(aq[mt][0], bk0, s4, 0, 0, 0);
        s4 = __builtin_amdgcn_mfma_f32_16x16x32_bf16(aq[mt][1], bk1, s4, 0, 0, 0);
#pragma unroll
        for (int r = 0; r < 4; r++) {
          int i = q0 + mt * 16 + quad * 4 + r;
          bool valid = (c == 12) || (j >= GG && j < SS && (j - i) <= WW && (i - j) <= WW);
          float s = valid ? s4[r] * scale : -1.0e9f;
          rmax[mt][r] = fmaxf(rmax[mt][r], s);
        }
      }
    }
  }
#pragma unroll
  for (int mt = 0; mt < 4; mt++)
#pragma unroll
    for (int r = 0; r < 4; r++) {
      float x = rmax[mt][r];
#pragma unroll
      for (int m = 1; m < 16; m <<= 1) x = fmaxf(x, __shfl_xor(x, m, 64));
      rmax[mt][r] = x;
    }

  // ---- Pass 2: exp + PV ----
  float rsum[4][4] = {};
  f32x4 oacc[4][4] = {};

  for (int c = 0; c < 13; c++) {
    const int j0 = (c < 12) ? (blk * WW - WW + c * 64) : 0;
    if (c < 12 && (j0 + 63 < GG || j0 >= SS)) continue;
    __syncthreads();
#pragma unroll
    for (int cpy = 0; cpy < 2; cpy++) {
      int r = sr + cpy * 32;
      int j = j0 + r;
      uint4 val = make_uint4(0, 0, 0, 0);
      uint4 vv  = make_uint4(0, 0, 0, 0);
      if (j >= 0 && j < SS) {
        val = *(const uint4*)&kb[(size_t)j * DHH + sc];
        vv  = *(const uint4*)&vb[(size_t)j * DHH + sc];
      }
      *(uint4*)&Ks[r * 64 + sc] = val;
      ushort_t tmp[8];
      *(uint4*)tmp = vv;
#pragma unroll
      for (int e = 0; e < 8; e++) Vts[(sc + e) * 64 + r] = tmp[e];
    }
    __syncthreads();
    ushort_t* Pw = &Ps[w][0];
#pragma unroll
    for (int nt = 0; nt < 4; nt++) {
      s16x8 bk0 = *(const s16x8*)&Ks[(nt * 16 + l16) * 64 + 0 + quad * 8];
      s16x8 bk1 = *(const s16x8*)&Ks[(nt * 16 + l16) * 64 + 32 + quad * 8];
      int j = j0 + nt * 16 + l16;
#pragma unroll
      for (int mt = 0; mt < 4; mt++) {
        f32x4 s4 = {0.f, 0.f, 0.f, 0.f};
        s4 = __builtin_amdgcn_mfma_f32_16x16x32_bf16(aq[mt][0], bk0, s4, 0, 0, 0);
        s4 = __builtin_amdgcn_mfma_f32_16x16x32_bf16(aq[mt][1], bk1, s4, 0, 0, 0);
#pragma unroll
        for (int r = 0; r < 4; r++) {
          int i = q0 + mt * 16 + quad * 4 + r;
          bool valid = (c == 12) || (j >= GG && j < SS && (j - i) <= WW && (i - j) <= WW);
          float p = 0.0f;
          if (valid) p = __expf(s4[r] * scale - rmax[mt][r]);
          rsum[mt][r] += p;
          Pw[(mt * 16 + quad * 4 + r) * 64 + nt * 16 + l16] = f2b(p);
        }
      }
    }
#pragma unroll
    for (int ll = 0; ll < 64; ll += 32) {
      s16x8 ap[4], bv[4];
#pragma unroll
      for (int mt = 0; mt < 4; mt++)
        ap[mt] = *(const s16x8*)&Pw[(mt * 16 + l16) * 64 + ll + quad * 8];
#pragma unroll
      for (int dt = 0; dt < 4; dt++)
        bv[dt] = *(const s16x8*)&Vts[(dt * 16 + l16) * 64 + ll + quad * 8];
#pragma unroll
      for (int mt = 0; mt < 4; mt++)
#pragma unroll
        for (int dt = 0; dt < 4; dt++)
          oacc[mt][dt] = __builtin_amdgcn_mfma_f32_16x16x32_bf16(ap[mt], bv[dt], oacc[mt][dt], 0, 0, 0);
    }
  }

#pragma unroll
  for (int mt = 0; mt < 4; mt++)
#pragma unroll
    for (int r = 0; r < 4; r++) {
      float x = rsum[mt][r];
#pragma unroll
      for (int m = 1; m < 16; m <<= 1) x += __shfl_xor(x, m, 64);
      rsum[mt][r] = 1.0f / x;
    }

#pragma unroll
  for (int mt = 0; mt < 4; mt++) {
#pragma unroll
    for (int r = 0; r < 4; r++) {
      int srow = q0 + mt * 16 + quad * 4 + r;
      size_t orow = ((size_t)b * SS + srow) * DD + h * DHH;
#pragma unroll
      for (int dt = 0; dt < 4; dt++)
        out[orow + dt * 16 + l16] = f2b(oacc[mt][dt][r] * rsum[mt][r]);
    }
  }
}

// ---------------------------------------------------------------------------
extern "C" void kernel_launch(void* const* d_in, const int* in_sizes, int n_in,
                              void* d_out, int out_size, void* d_ws, size_t ws_size,
                              hipStream_t stream) {
  // Input order: dict order confirmed (round 5: in_sizes[0]==8388608 branch
  // reproduced rounds 3/4 bit-identically). Dtype fp32 confirmed by round-5
  // on-device detector. Keep size-based resolution as a safety net.
  const float *x, *Wq, *Wk, *Wv, *Wo;
  if (n_in == 5 && in_sizes[4] == 8388608) {   // alphabetical fallback
    Wk = (const float*)d_in[0]; Wo = (const float*)d_in[1];
    Wq = (const float*)d_in[2]; Wv = (const float*)d_in[3];
    x  = (const float*)d_in[4];
  } else {                                      // dict order (confirmed)
    x  = (const float*)d_in[0]; Wq = (const float*)d_in[1];
    Wk = (const float*)d_in[2]; Wv = (const float*)d_in[3];
    Wo = (const float*)d_in[4];
  }
  float* out = (float*)d_out;   // FP32 output (matches fp32 reference dtype)

  // Workspace: [WqT|WkT|WvT] 6MiB | WoT 2MiB | q 16MiB | k 16MiB | v 16MiB | attn 16MiB
  char* ws = (char*)d_ws;
  ushort_t* wqkvT = (ushort_t*)(ws);
  ushort_t* woT   = (ushort_t*)(ws + 6291456);
  ushort_t* qbuf  = (ushort_t*)(ws + 8388608);
  ushort_t* kbuf  = (ushort_t*)(ws + 8388608 + 16777216);
  ushort_t* vbuf  = (ushort_t*)(ws + 8388608 + 2 * 16777216);
  ushort_t* attn  = (ushort_t*)(ws + 8388608 + 3 * 16777216);

  transpose_w<<<dim3(16, 16, 4), 256, 0, stream>>>(Wq, Wk, Wv, Wo, wqkvT);
  gemm_bt<0><<<dim3(64, 24), 256, 0, stream>>>((const void*)x, wqkvT, qbuf, kbuf, vbuf, nullptr, 1024);
  attn_kernel<<<dim3(NBLK, HH, BB), 256, 0, stream>>>(qbuf, kbuf, vbuf, attn);
  gemm_bt<1><<<dim3(64, 8), 256, 0, stream>>>((const void*)attn, woT, nullptr, nullptr, nullptr, out, 1024);
}

// Round 8
// 348.440 us; speedup vs baseline: 1.0543x; 1.0543x over previous
//
#include <hip/hip_runtime.h>

// Problem constants
#define BB   2
#define SS   4096
#define DD   1024
#define HH   16
#define DHH  64
#define WW   256
#define GG   64
#define NBLK 16    // S/W

typedef unsigned short ushort_t;
typedef short  s16x8 __attribute__((ext_vector_type(8)));
typedef float  f32x4 __attribute__((ext_vector_type(4)));

// fp32 -> bf16 round-to-nearest-even, raw bits
__device__ __forceinline__ ushort_t f2b(float f) {
  unsigned int u = __builtin_bit_cast(unsigned int, f);
  unsigned int r = (u + 0x7fffu + ((u >> 16) & 1u)) >> 16;
  return (ushort_t)r;
}

// 2^x via v_exp_f32 (NOT __exp2f — that name collides with glibc math.h).
__device__ __forceinline__ float exp2f_fast(float x) {
  return __builtin_amdgcn_exp2f(x);
}

// Async 16B global->LDS DMA (m97 pattern). LDS dst must be wave-uniform
// base + lane*16 (m104/m108); all call sites below satisfy this (offset
// == tid*16 within each wave's segment).
__device__ __forceinline__ void gld16(const void* g, void* l) {
  __builtin_amdgcn_global_load_lds(
      (const __attribute__((address_space(1))) void*)g,
      (__attribute__((address_space(3))) void*)l, 16, 0, 0);
}

// ---------------------------------------------------------------------------
// x (fp32) -> bf16, flat. 4096 blocks x 256 thr x 8 elems.
// ---------------------------------------------------------------------------
__global__ __launch_bounds__(256) void xcast(
    const float* __restrict__ x, ushort_t* __restrict__ xb) {
  size_t i = ((size_t)blockIdx.x * 256 + threadIdx.x) * 8;
  float4 f0 = *(const float4*)&x[i];
  float4 f1 = *(const float4*)&x[i + 4];
  ushort_t t[8];
  t[0] = f2b(f0.x); t[1] = f2b(f0.y); t[2] = f2b(f0.z); t[3] = f2b(f0.w);
  t[4] = f2b(f1.x); t[5] = f2b(f1.y); t[6] = f2b(f1.z); t[7] = f2b(f1.w);
  *(uint4*)&xb[i] = *(const uint4*)t;
}

// ---------------------------------------------------------------------------
// Transpose + fp32->bf16 the four weight matrices into (n,k) bf16 layout.
// ---------------------------------------------------------------------------
__global__ __launch_bounds__(256) void transpose_w(
    const float* __restrict__ Wq, const float* __restrict__ Wk,
    const float* __restrict__ Wv, const float* __restrict__ Wo,
    ushort_t* __restrict__ outBase) {
  const float* src = (blockIdx.z == 0) ? Wq : (blockIdx.z == 1) ? Wk
                    : (blockIdx.z == 2) ? Wv : Wo;
  ushort_t* dst = outBase + (size_t)blockIdx.z * (1024 * 1024);
  __shared__ __align__(16) ushort_t t[64][72];
  const int tid = threadIdx.x;
  const int bx = blockIdx.x * 64, by = blockIdx.y * 64;
  const int c4 = (tid & 15) * 4;
  const int r16 = tid >> 4;
  for (int rr = r16; rr < 64; rr += 16) {
    float4 f = *(const float4*)&src[(size_t)(by + rr) * 1024 + bx + c4];
    t[c4 + 0][rr] = f2b(f.x);
    t[c4 + 1][rr] = f2b(f.y);
    t[c4 + 2][rr] = f2b(f.z);
    t[c4 + 3][rr] = f2b(f.w);
  }
  __syncthreads();
  const int sr = tid >> 3;
  const int sc = (tid & 7) * 8;
  for (int rr = sr; rr < 64; rr += 32) {
    *(uint4*)&dst[(size_t)(bx + rr) * 1024 + by + sc] = *(const uint4*)&t[rr][sc];
  }
}

// ---------------------------------------------------------------------------
// GEMM: C(M,N) = A(M,K) @ Bt(N,K)^T, bf16 in, fp32 acc.
// global_load_lds 16B staging for both A and B (m97 structure).
// MODE 0: N=3072 QKV; q,k head-split (B,H,S,DH); v TRANSPOSED (B,H,DH,S).
// MODE 1: fp32 row-major C to Of (the final output).
// ---------------------------------------------------------------------------
template <int MODE>
__global__ __launch_bounds__(256) void gemm_bt(
    const ushort_t* __restrict__ A, const ushort_t* __restrict__ Bt,
    ushort_t* __restrict__ O0, ushort_t* __restrict__ O1,
    ushort_t* __restrict__ O2, float* __restrict__ Of, int K) {
  __shared__ __align__(16) ushort_t As[128 * 64];
  __shared__ __align__(16) ushort_t Bs[128 * 64];
  const int tid  = threadIdx.x;
  const int lane = tid & 63;
  const int w    = tid >> 6;
  const int quad = lane >> 4;
  const int l16  = lane & 15;
  const int bm = blockIdx.x * 128;
  const int bn = blockIdx.y * 128;
  const int sr = tid >> 3;
  const int sc = (tid & 7) * 8;
  const int wm = (w & 1) * 64;
  const int wn = (w >> 1) * 64;

  f32x4 acc[4][4] = {};

  for (int k0 = 0; k0 < K; k0 += 64) {
    __syncthreads();
#pragma unroll
    for (int cpy = 0; cpy < 4; cpy++) {
      int r = sr + cpy * 32;
      gld16(&A[(size_t)(bm + r) * K + k0 + sc], &As[r * 64 + sc]);
      gld16(&Bt[(size_t)(bn + r) * K + k0 + sc], &Bs[r * 64 + sc]);
    }
    __syncthreads();
#pragma unroll
    for (int kk = 0; kk < 64; kk += 32) {
      s16x8 a[4], b[4];
#pragma unroll
      for (int t = 0; t < 4; t++)
        a[t] = *(const s16x8*)&As[(wm + t * 16 + l16) * 64 + kk + quad * 8];
#pragma unroll
      for (int t = 0; t < 4; t++)
        b[t] = *(const s16x8*)&Bs[(wn + t * 16 + l16) * 64 + kk + quad * 8];
#pragma unroll
      for (int i = 0; i < 4; i++)
#pragma unroll
        for (int j = 0; j < 4; j++)
          acc[i][j] = __builtin_amdgcn_mfma_f32_16x16x32_bf16(a[i], b[j], acc[i][j], 0, 0, 0);
    }
  }

  // Epilogue. C/D layout: row = quad*4 + reg, col = lane&15.
#pragma unroll
  for (int i = 0; i < 4; i++) {
#pragma unroll
    for (int j = 0; j < 4; j++) {
#pragma unroll
      for (int r = 0; r < 4; r++) {
        int m = bm + wm + i * 16 + quad * 4 + r;
        int n = bn + wn + j * 16 + l16;
        if (MODE == 0) {
          ushort_t val = f2b(acc[i][j][r]);
          int n1 = n & 1023;
          int h = n1 >> 6, dh = n1 & 63;
          int b = m >> 12, s = m & 4095;
          if (n < 1024) {
            O0[(((size_t)b * HH + h) * SS + s) * DHH + dh] = val;      // q: (B,H,S,DH)
          } else if (n < 2048) {
            O1[(((size_t)b * HH + h) * SS + s) * DHH + dh] = val;      // k: (B,H,S,DH)
          } else {
            O2[(((size_t)b * HH + h) * DHH + dh) * SS + s] = val;      // v: (B,H,DH,S) transposed
          }
        } else {
          Of[(size_t)m * DD + n] = acc[i][j][r];   // fp32 output
        }
      }
    }
  }
}

// ---------------------------------------------------------------------------
// Attention v2: single-pass shift-free softmax (scores bounded ~2.5; softmax
// shift-invariance validated round 3 vs 4). grid (NBLK, H, B), 4 waves; wave
// w owns 64 queries. 12 local chunks + 1 global chunk of 64 keys; K and
// V^T staged via global_load_lds (all rows provably in-bounds). P goes
// through XOR-swizzled per-wave LDS tile (write ~conflict-free).
// Per-wave compute skip on workless chunks (barriers stay uniform).
// Output (B, S, H*DH) bf16.
// ---------------------------------------------------------------------------
__global__ __launch_bounds__(256, 2) void attn_kernel(
    const ushort_t* __restrict__ q, const ushort_t* __restrict__ k,
    const ushort_t* __restrict__ vT, ushort_t* __restrict__ out) {
  const int blk = blockIdx.x;
  const int h   = blockIdx.y;
  const int b   = blockIdx.z;
  const int tid  = threadIdx.x;
  const int lane = tid & 63;
  const int w    = tid >> 6;
  const int quad = lane >> 4;
  const int l16  = lane & 15;

  const size_t bh = ((size_t)b * HH + h) * SS * DHH;
  const ushort_t* qb  = q + bh;
  const ushort_t* kb  = k + bh;
  const ushort_t* vtb = vT + bh;   // layout [dh][s], row stride SS

  __shared__ __align__(16) ushort_t Ks[64 * 64];
  __shared__ __align__(16) ushort_t Vts[64 * 64];     // [dh][l] via DMA from vT
  __shared__ __align__(16) ushort_t Ps[4][64 * 64];   // XOR-swizzled P tiles

  const int q0 = blk * WW + w * 64;
  const float C = 0.18033688011112042f;   // 0.125 * log2(e)

  // Q fragments (A-operand: m = lane&15, k = quad*8+j)
  s16x8 aq[4][2];
#pragma unroll
  for (int mt = 0; mt < 4; mt++)
#pragma unroll
    for (int x = 0; x < 2; x++)
      aq[mt][x] = *(const s16x8*)&qb[(size_t)(q0 + mt * 16 + l16) * DHH + x * 32 + quad * 8];

  float rsum[4][4] = {};
  f32x4 oacc[4][4] = {};
  const int srow = tid >> 3;          // staging row 0..31
  const int soff = (tid & 7) * 8;     // staging 16B chunk

  for (int c = 0; c <= 12; c++) {
    const int j0 = (c < 12) ? (blk * WW - WW + c * 64) : 0;
    if (c < 12 && (j0 < GG || j0 >= SS)) continue;   // block-uniform skip
    __syncthreads();
    // Stage K rows [j0, j0+64) and V^T rows (dh) cols [j0, j0+64) — pure DMA.
    gld16(&kb[(size_t)(j0 + srow) * DHH + soff],        &Ks[srow * 64 + soff]);
    gld16(&kb[(size_t)(j0 + srow + 32) * DHH + soff],   &Ks[(srow + 32) * 64 + soff]);
    gld16(&vtb[(size_t)srow * SS + j0 + soff],          &Vts[srow * 64 + soff]);
    gld16(&vtb[(size_t)(srow + 32) * SS + j0 + soff],   &Vts[(srow + 32) * 64 + soff]);
    __syncthreads();

    const int dlt = j0 - q0;
    const bool haswork = (c == 12) || (dlt >= -319 && dlt <= 319);
    if (!haswork) continue;
    const bool needmask = (c < 12) && (dlt < -193 || dlt > 193);

    ushort_t* Pw = &Ps[w][0];
#pragma unroll
    for (int nt = 0; nt < 4; nt++) {
      s16x8 bk0 = *(const s16x8*)&Ks[(nt * 16 + l16) * 64 + 0 + quad * 8];
      s16x8 bk1 = *(const s16x8*)&Ks[(nt * 16 + l16) * 64 + 32 + quad * 8];
      const int j = j0 + nt * 16 + l16;
#pragma unroll
      for (int mt = 0; mt < 4; mt++) {
        f32x4 s4 = {0.f, 0.f, 0.f, 0.f};
        s4 = __builtin_amdgcn_mfma_f32_16x16x32_bf16(aq[mt][0], bk0, s4, 0, 0, 0);
        s4 = __builtin_amdgcn_mfma_f32_16x16x32_bf16(aq[mt][1], bk1, s4, 0, 0, 0);
#pragma unroll
        for (int r = 0; r < 4; r++) {
          float p;
          if (needmask) {
            int i = q0 + mt * 16 + quad * 4 + r;
            int d = j - i;
            p = (d <= (int)WW && d >= -(int)WW) ? exp2f_fast(s4[r] * C) : 0.0f;
          } else {
            p = exp2f_fast(s4[r] * C);
          }
          rsum[mt][r] += p;
          const int row = mt * 16 + quad * 4 + r;
          const int col = nt * 16 + l16;
          // XOR swizzle on 8-elem (16B) chunks: chunk' = chunk ^ (row&7)
          Pw[row * 64 + (((col >> 3) ^ (row & 7)) << 3) + (col & 7)] = f2b(p);
        }
      }
    }
    // PV: A = P (swizzled read), Bt = V^T rows (dh).
#pragma unroll
    for (int ll = 0; ll < 64; ll += 32) {
      s16x8 ap[4], bv[4];
#pragma unroll
      for (int mt = 0; mt < 4; mt++) {
        const int row = mt * 16 + l16;
        const int chunk = (ll >> 3) + quad;          // == (ll + quad*8) >> 3
        ap[mt] = *(const s16x8*)&Pw[row * 64 + ((chunk ^ (row & 7)) << 3)];
      }
#pragma unroll
      for (int dt = 0; dt < 4; dt++)
        bv[dt] = *(const s16x8*)&Vts[(dt * 16 + l16) * 64 + ll + quad * 8];
#pragma unroll
      for (int mt = 0; mt < 4; mt++)
#pragma unroll
        for (int dt = 0; dt < 4; dt++)
          oacc[mt][dt] = __builtin_amdgcn_mfma_f32_16x16x32_bf16(ap[mt], bv[dt], oacc[mt][dt], 0, 0, 0);
    }
  }

  // Row-sum reduction across the 16 lanes holding each row, then normalize.
#pragma unroll
  for (int mt = 0; mt < 4; mt++)
#pragma unroll
    for (int r = 0; r < 4; r++) {
      float x = rsum[mt][r];
#pragma unroll
      for (int m = 1; m < 16; m <<= 1) x += __shfl_xor(x, m, 64);
      rsum[mt][r] = 1.0f / x;
    }

#pragma unroll
  for (int mt = 0; mt < 4; mt++) {
#pragma unroll
    for (int r = 0; r < 4; r++) {
      int srow2 = q0 + mt * 16 + quad * 4 + r;
      size_t orow = ((size_t)b * SS + srow2) * DD + h * DHH;
#pragma unroll
      for (int dt = 0; dt < 4; dt++)
        out[orow + dt * 16 + l16] = f2b(oacc[mt][dt][r] * rsum[mt][r]);
    }
  }
}

// ---------------------------------------------------------------------------
extern "C" void kernel_launch(void* const* d_in, const int* in_sizes, int n_in,
                              void* d_out, int out_size, void* d_ws, size_t ws_size,
                              hipStream_t stream) {
  const float *x, *Wq, *Wk, *Wv, *Wo;
  if (n_in == 5 && in_sizes[4] == 8388608) {   // alphabetical fallback
    Wk = (const float*)d_in[0]; Wo = (const float*)d_in[1];
    Wq = (const float*)d_in[2]; Wv = (const float*)d_in[3];
    x  = (const float*)d_in[4];
  } else {                                      // dict order (confirmed round 5/6)
    x  = (const float*)d_in[0]; Wq = (const float*)d_in[1];
    Wk = (const float*)d_in[2]; Wv = (const float*)d_in[3];
    Wo = (const float*)d_in[4];
  }
  float* out = (float*)d_out;   // fp32 output (confirmed round 6)

  // Workspace (72 MiB, proven available):
  // [WqT|WkT|WvT] 6MiB | WoT 2MiB | q 16MiB | k 16MiB | vT 16MiB | attn/xb 16MiB
  // xb (bf16 x) shares the attn slot: consumed by gemm<0> before attn writes.
  char* ws = (char*)d_ws;
  ushort_t* wqkvT = (ushort_t*)(ws);
  ushort_t* woT   = (ushort_t*)(ws + 6291456);
  ushort_t* qbuf  = (ushort_t*)(ws + 8388608);
  ushort_t* kbuf  = (ushort_t*)(ws + 8388608 + 16777216);
  ushort_t* vbuf  = (ushort_t*)(ws + 8388608 + 2 * 16777216);
  ushort_t* attn  = (ushort_t*)(ws + 8388608 + 3 * 16777216);
  ushort_t* xb    = attn;   // alias, lifetime-disjoint

  xcast<<<dim3(4096), 256, 0, stream>>>(x, xb);
  transpose_w<<<dim3(16, 16, 4), 256, 0, stream>>>(Wq, Wk, Wv, Wo, wqkvT);
  gemm_bt<0><<<dim3(64, 24), 256, 0, stream>>>(xb, wqkvT, qbuf, kbuf, vbuf, nullptr, 1024);
  attn_kernel<<<dim3(NBLK, HH, BB), 256, 0, stream>>>(qbuf, kbuf, vbuf, attn);
  gemm_bt<1><<<dim3(64, 8), 256, 0, stream>>>(attn, woT, nullptr, nullptr, nullptr, out, 1024);
}